// Round 1
// 233.544 us; speedup vs baseline: 1.0141x; 1.0141x over previous
//
#include <hip/hip_runtime.h>

// Sobel |gx|+|gy|+eps, SAME zero padding. Input (32,1,1024,1024) fp32.
//
// R4: software-pipelined register row buffer (depth NR=6: 3 live rows + 3 in
// flight). Theory from R3 counters (84us, 2.5TB/s, VALUBusy 11%, VGPR=28):
// kernel was latency/drain-bound -- prefetch distance 1 with 2-of-3 load
// instructions being divergent scalar halo dwords, and a vmcnt drain per row.
// Changes:
//  - each row fetched as ONE unaligned dwordx4 at x0-1 + ONE dwordx2 at x0+3
//    (exactly the 6 floats needed; 2 independent vector loads, zero scalar
//    halo loads, zero shuffles, all lanes uniform, never reads out of bounds)
//  - circular buffer fully unrolled -> static indices (no scratch), zero
//    register-rotation movs, loads issued 4 rows (~500 cyc) before consume
//    -> ~8 loads / 2KB outstanding per wave at steady state, counted vmcnt
//  - edge lanes (x==0 / x==1020) fixed with 6 cndmask at first consume
//  - __launch_bounds__(256,8) pins VGPR<=64 so 32 waves/CU stay resident
// XCD swizzle + nontemporal stores kept from R3.

#define W 1024
#define H 1024
#define R 16          // rows per block strip (64 strips/image)
#define NR 6          // row slots in the circular buffer
#define EPS 1e-5f

typedef float v4f __attribute__((ext_vector_type(4)));
typedef float v2f __attribute__((ext_vector_type(2)));
typedef v4f v4f_u __attribute__((aligned(4)));   // 4B-aligned vector loads:
typedef v2f v2f_u __attribute__((aligned(4)));   // global_load_dwordx4/x2 allow it

// Issue the loads for row y into slot s (6 floats: r[x0-1 .. x0+4], raw).
// Loads are NOT consumed here -- waitcnt lands at first consume (fix_edges).
__device__ __forceinline__ void issue_row(const float* __restrict__ base, int y,
                                          int xl, int xr, float* s) {
    if ((unsigned)y < (unsigned)H) {          // block-uniform scalar branch
        const float* r = base + (size_t)y * W;
        v4f a = *(const v4f_u*)(r + xl);      // r[x0-1 .. x0+2]  (xl=max(x0-1,0))
        v2f b = *(const v2f_u*)(r + xr);      // r[x0+3 .. x0+4]  (xr clamped to W-2)
        s[0] = a.x; s[1] = a.y; s[2] = a.z; s[3] = a.w;
        s[4] = b.x; s[5] = b.y;
    } else {
        s[0] = s[1] = s[2] = s[3] = s[4] = s[5] = 0.f;
    }
}

// First consume of a row: repair the two edge lanes with selects.
// thread x0==0   loaded a at x0 (not x0-1): shift right, w0 = 0 (SAME pad)
// thread x0==W-4 loaded b at W-2:           w4 = b.y, w5 = 0
__device__ __forceinline__ void fix_edges(float* s, bool t0, bool tN) {
    float n3 = t0 ? s[2] : s[3];
    float n2 = t0 ? s[1] : s[2];
    float n1 = t0 ? s[0] : s[1];
    float n0 = t0 ? 0.f  : s[0];
    s[0] = n0; s[1] = n1; s[2] = n2; s[3] = n3;
    float n4 = tN ? s[5] : s[4];
    float n5 = tN ? 0.f  : s[5];
    s[4] = n4; s[5] = n5;
}

__global__ __launch_bounds__(256, 8) void sobel_kernel(const float* __restrict__ in,
                                                       float* __restrict__ out) {
    // XCD swizzle (unchanged from R3): same-XCD blocks get 8 adjacent strips
    // so shared halo rows stay in that XCD's L2.
    const int b = blockIdx.x;                  // 0..2047
    const int t = ((b & 255) << 3) | (b >> 8); // bijective swizzle
    const int img = t >> 6;                    // 64 strips per image
    const int ty = (t & 63) * R;               // first output row of strip
    const int x0 = threadIdx.x << 2;

    const int  xl = (x0 == 0)     ? 0       : x0 - 1;
    const int  xr = (x0 == W - 4) ? (W - 2) : x0 + 3;
    const bool t0 = (x0 == 0);
    const bool tN = (x0 == W - 4);

    const float* base  = in  + (size_t)img * (W * H);
    float*       obase = out + (size_t)img * (W * H);

    float rs[NR][6];   // slot(row ty-1+k) = k % NR; fully static after unroll

    // Prologue: issue rows ty-1 .. ty+4 (6 rows, ~12 loads in flight).
#pragma unroll
    for (int k = 0; k < NR; ++k)
        issue_row(base, ty - 1 + k, xl, xr, rs[k]);
    fix_edges(rs[0], t0, tN);   // row ty-1
    fix_edges(rs[1], t0, tN);   // row ty

#pragma unroll
    for (int i = 0; i < R; ++i) {
        // First consume of row ty+i+1 (loaded 4 iterations ago).
        fix_edges(rs[(i + 2) % NR], t0, tN);

        float* Tr = rs[(i + 0) % NR];   // row ty+i-1
        float* Mr = rs[(i + 1) % NR];   // row ty+i
        float* Br = rs[(i + 2) % NR];   // row ty+i+1

        v4f o;
#pragma unroll
        for (int j = 0; j < 4; ++j) {
            // Sobel X: [[-1,0,1],[-2,0,2],[-1,0,1]]
            float gx = (Tr[j + 2] - Tr[j]) + 2.0f * (Mr[j + 2] - Mr[j]) + (Br[j + 2] - Br[j]);
            // Sobel Y: [[-1,-2,-1],[0,0,0],[1,2,1]]
            float gy = (Br[j] + 2.0f * Br[j + 1] + Br[j + 2]) - (Tr[j] + 2.0f * Tr[j + 1] + Tr[j + 2]);
            o[j] = fabsf(gx) + fabsf(gy) + EPS;
        }
        __builtin_nontemporal_store(o, (v4f*)(obase + (size_t)(ty + i) * W + x0));

        // Refill the just-retired T slot with row ty+i+5 (consumed at i+4).
        // Rows beyond ty+16 are never needed -> compile-time guard, no waste.
        if (i + 5 <= R)
            issue_row(base, ty + i + 5, xl, xr, rs[i % NR]);
    }
}

extern "C" void kernel_launch(void* const* d_in, const int* in_sizes, int n_in,
                              void* d_out, int out_size, void* d_ws, size_t ws_size,
                              hipStream_t stream) {
    const float* x = (const float*)d_in[0];
    float* outp = (float*)d_out;
    const int N = 32;
    dim3 grid(N * (H / R));   // 32 * 64 = 2048 blocks
    dim3 block(256);
    sobel_kernel<<<grid, block, 0, stream>>>(x, outp);
}